// Round 2
// baseline (370.762 us; speedup 1.0000x reference)
//
#include <hip/hip_runtime.h>

typedef unsigned short u16;
typedef unsigned int u32;
typedef __bf16 bf16x8 __attribute__((ext_vector_type(8)));
typedef float f32x4 __attribute__((ext_vector_type(4)));

#define MFMA16(a,b,c) __builtin_amdgcn_mfma_f32_16x16x32_bf16((a),(b),(c),0,0,0)

__device__ __forceinline__ float b2f(u16 u) {
    u32 v = ((u32)u) << 16;
    return __builtin_bit_cast(float, v);
}
__device__ __forceinline__ u16 f2b(float f) {
    u32 u = __builtin_bit_cast(u32, f);
    u = u + 0x7FFFu + ((u >> 16) & 1u);   // RNE
    return (u16)(u >> 16);
}

// async global->LDS, 16B per lane. LDS dest is wave-uniform base + lane*16.
__device__ __forceinline__ void gload_lds16(const u16* g, u16* l) {
    __builtin_amdgcn_global_load_lds(
        (__attribute__((address_space(1))) void*)g,
        (__attribute__((address_space(3))) void*)l, 16, 0, 0);
}

// load 8 contiguous elements at element-offset `off`, as 8 bf16 (uint4).
__device__ __forceinline__ uint4 load8_bf16(const void* base, size_t off, int f32m) {
    if (f32m) {
        const float* p = (const float*)base + off;
        float4 a = *(const float4*)p;
        float4 b = *(const float4*)(p + 4);
        union { u16 u[8]; uint4 v; } t;
        t.u[0] = f2b(a.x); t.u[1] = f2b(a.y); t.u[2] = f2b(a.z); t.u[3] = f2b(a.w);
        t.u[4] = f2b(b.x); t.u[5] = f2b(b.y); t.u[6] = f2b(b.z); t.u[7] = f2b(b.w);
        return t.v;
    }
    return *(const uint4*)((const u16*)base + off);
}

// ---- dtype detector: even-indexed u16s of f32 data are random mantissa bits
__global__ __launch_bounds__(256) void k_detect(const u16* __restrict__ x, int* flag) {
    __shared__ int c;
    if (threadIdx.x == 0) c = 0;
    __syncthreads();
    int my = 0;
    #pragma unroll
    for (int j = 0; j < 16; ++j) {
        u16 v = x[2 * (threadIdx.x + 256 * j)];
        if (((v >> 7) & 0xFF) >= 0x90) ++my;
    }
    atomicAdd(&c, my);
    __syncthreads();
    if (threadIdx.x == 0) *flag = (c > 64) ? 1 : 0;
}

__global__ __launch_bounds__(256) void k_cvt_bias(
    const void* __restrict__ ba, const void* __restrict__ bp,
    const int* __restrict__ flag, u16* __restrict__ bac, u16* __restrict__ bpc)
{
    const int f32m = *flag;
    const int t = threadIdx.x;
    #pragma unroll
    for (int j = 0; j < 12; ++j) {
        int i = t + 256 * j;
        if (i < 3072) bac[i] = f32m ? f2b(((const float*)ba)[i]) : ((const u16*)ba)[i];
    }
    #pragma unroll
    for (int j = 0; j < 4; ++j) {
        int i = t + 256 * j;
        if (i < 1024) bpc[i] = f32m ? f2b(((const float*)bp)[i]) : ((const u16*)bp)[i];
    }
}

// ---- one-time x f32->bf16 conversion (f32 mode only; bf16 mode uses x directly)
__global__ __launch_bounds__(256) void k_cvt_x(
    const float* __restrict__ x, const int* __restrict__ flag, u16* __restrict__ out)
{
    if (!*flag) return;
    size_t i = ((size_t)blockIdx.x * 256 + threadIdx.x) * 8;
    float4 a = *(const float4*)(x + i);
    float4 b = *(const float4*)(x + i + 4);
    union { u16 u[8]; uint4 v; } t;
    t.u[0] = f2b(a.x); t.u[1] = f2b(a.y); t.u[2] = f2b(a.z); t.u[3] = f2b(a.w);
    t.u[4] = f2b(b.x); t.u[5] = f2b(b.y); t.u[6] = f2b(b.z); t.u[7] = f2b(b.w);
    *(uint4*)(out + i) = t.v;
}

// ---------------- transpose+convert: src[R][Cc] -> dst[Cc][R] bf16 ---------
__global__ __launch_bounds__(256) void k_transpose(
    const void* __restrict__ src, u16* __restrict__ dst, int R, int Cc,
    const int* __restrict__ flag)
{
    __shared__ u16 tile[64 * 72];
    const int f32m = *flag;
    const int t = threadIdx.x;
    const int c0 = blockIdx.x * 64, r0 = blockIdx.y * 64;
    #pragma unroll
    for (int i = 0; i < 2; ++i) {
        int ch = t + 256 * i;            // 512 chunks of 8
        int r = ch >> 3, c8 = (ch & 7) * 8;
        *(uint4*)&tile[r * 72 + c8] =
            load8_bf16(src, (size_t)(r0 + r) * Cc + c0 + c8, f32m);
    }
    __syncthreads();
    #pragma unroll
    for (int i = 0; i < 2; ++i) {
        int ch = t + 256 * i;
        int r = ch >> 3, c8 = (ch & 7) * 8;
        union { u16 u[8]; uint4 v; } tmp;
        #pragma unroll
        for (int j = 0; j < 8; ++j) tmp.u[j] = tile[(c8 + j) * 72 + r];
        *(uint4*)&dst[(size_t)(c0 + r) * R + r0 + c8] = tmp.v;
    }
}

// ---------------- QKV GEMM: A[8192,1024] x Bt[3072,1024]^T + bias ----------
// m97 structure: linear [128][64] bf16 LDS tiles, global_load_lds width-16
// staging, 2 barriers per K-step.
__global__ __launch_bounds__(256) void k_gemm_qkv(
    const void* __restrict__ x, const u16* __restrict__ Abf,
    const u16* __restrict__ Bt, const u16* __restrict__ bias,
    const int* __restrict__ flag,
    u16* __restrict__ Ql, u16* __restrict__ Kl, u16* __restrict__ Vt)
{
    constexpr int K = 1024;
    __shared__ __align__(16) u16 As[128 * 64];
    __shared__ __align__(16) u16 Bs[128 * 64];
    const int t = threadIdx.x;
    const int lane = t & 63, w = t >> 6;
    const int quad = lane >> 4, m16 = lane & 15;
    const int wm = (w >> 1) * 64, wn = (w & 1) * 64;
    const int m0 = blockIdx.x * 128, n0 = blockIdx.y * 128;
    const int lr = lane >> 3;            // row within 8-row chunk
    const int lc = (lane & 7) * 8;       // elem col within 64
    const u16* A = (*flag) ? Abf : (const u16*)x;

    const f32x4 z = {0.f, 0.f, 0.f, 0.f};
    f32x4 acc[4][4];
    #pragma unroll
    for (int mi = 0; mi < 4; ++mi)
        #pragma unroll
        for (int ni = 0; ni < 4; ++ni) acc[mi][ni] = z;

    for (int k0 = 0; k0 < K; k0 += 64) {
        __syncthreads();                 // previous compute done reading LDS
        #pragma unroll
        for (int i = 0; i < 4; ++i) {
            const int chunk = w * 4 + i;               // wave-uniform
            const int row = chunk * 8 + lr;
            gload_lds16(&A [(size_t)(m0 + row) * K + k0 + lc], &As[chunk * 512]);
            gload_lds16(&Bt[(size_t)(n0 + row) * K + k0 + lc], &Bs[chunk * 512]);
        }
        __syncthreads();                 // compiler drains vmcnt(0) here
        #pragma unroll
        for (int kk = 0; kk < 2; ++kk) {
            bf16x8 af[4], bfr[4];
            #pragma unroll
            for (int mi = 0; mi < 4; ++mi)
                af[mi] = *(const bf16x8*)&As[(wm + mi * 16 + m16) * 64 + kk * 32 + quad * 8];
            #pragma unroll
            for (int ni = 0; ni < 4; ++ni)
                bfr[ni] = *(const bf16x8*)&Bs[(wn + ni * 16 + m16) * 64 + kk * 32 + quad * 8];
            #pragma unroll
            for (int mi = 0; mi < 4; ++mi)
                #pragma unroll
                for (int ni = 0; ni < 4; ++ni)
                    acc[mi][ni] = MFMA16(af[mi], bfr[ni], acc[mi][ni]);
        }
    }

    const int sec = n0 >> 10;  // 0=Q,1=K,2=V — uniform per block (128 | 1024)
    const float qscale = (sec == 0) ? 0.18033688011112042f : 1.0f;  // 0.125*log2e
    #pragma unroll
    for (int mi = 0; mi < 4; ++mi) {
        #pragma unroll
        for (int ni = 0; ni < 4; ++ni) {
            int gn = n0 + wn + ni * 16 + m16;
            int sn = gn & 1023;
            int h = sn >> 6, d = sn & 63;
            float bv = b2f(bias[gn]);
            #pragma unroll
            for (int v = 0; v < 4; ++v) {
                int gm = m0 + wm + mi * 16 + quad * 4 + v;
                int bb = gm >> 11, tt = gm & 2047;
                u16 o = f2b((acc[mi][ni][v] + bv) * qscale);
                size_t bh = (size_t)(bb * 16 + h);
                if (sec == 0)      Ql[(bh * 2048 + tt) * 64 + d] = o;
                else if (sec == 1) Kl[(bh * 2048 + tt) * 64 + d] = o;
                else               Vt[(bh * 64 + d) * 2048 + tt] = o;
            }
        }
    }
}

// ---------------- flash attention: block = (128 q rows, one (b,h)) ---------
// Swapped QK^T: accs = mfma(K_frag, Q_frag) = S^T, so each lane holds
// 4-consecutive-kv runs -> P store is ds_write_b64 of compiler-packed bf16
// (v_cvt_pk_bf16_f32) instead of 64 scalar ds_write_b16.
// K fragments read once for both q-strips; V fragments hoisted to registers
// once per tile (LDS reads per wave-tile: 72 -> 40 b128-equiv).
__global__ __launch_bounds__(256) void k_attn(
    u16* __restrict__ Ql, const u16* __restrict__ Kl, const u16* __restrict__ Vt)
{
    __shared__ u16 Ks[128 * 72];
    __shared__ u16 Vs[64 * 136];
    __shared__ u16 Ps[64 * 136];
    const int t = threadIdx.x;
    const int lane = t & 63, w = t >> 6;
    const int quad = lane >> 4, m16 = lane & 15;
    const int qb = 15 - (blockIdx.x >> 6);
    const int bh = blockIdx.x & 63;
    const int q0 = qb * 128;

    // Q fragments for both strips, registers for the whole block
    bf16x8 fq[2][2];
    #pragma unroll
    for (int s = 0; s < 2; ++s) {
        const u16* Qp = Ql + ((size_t)bh * 2048 + q0 + s * 64 + w * 16 + m16) * 64;
        fq[s][0] = *(const bf16x8*)&Qp[quad * 8];
        fq[s][1] = *(const bf16x8*)&Qp[32 + quad * 8];
    }

    const f32x4 z = {0.f, 0.f, 0.f, 0.f};
    f32x4 acco[2][4] = {{z, z, z, z}, {z, z, z, z}};
    f32x4 accl[2] = {z, z};
    bf16x8 ones;
    #pragma unroll
    for (int j = 0; j < 8; ++j) ones[j] = (__bf16)1.0f;

    const int ktmax = qb;
    const u16* Kbase = Kl + (size_t)bh * 2048 * 64;
    const u16* Vbase = Vt + (size_t)bh * 64 * 2048;

    uint4 kreg[4], vreg[4];
    #pragma unroll
    for (int i = 0; i < 4; ++i) {
        int c = t + 256 * i;
        int r = c >> 3, col = (c & 7) * 8;
        kreg[i] = *(const uint4*)&Kbase[(size_t)r * 64 + col];          // kt=0
        int dd = c >> 4, kvc = (c & 15) * 8;
        vreg[i] = *(const uint4*)&Vbase[(size_t)dd * 2048 + kvc];       // kt=0
    }

    const int pr = (w * 16 + m16) * 136;   // wave-private Ps row (bytes/2)

    for (int kt = 0; kt <= ktmax; ++kt) {
        __syncthreads();
        #pragma unroll
        for (int i = 0; i < 4; ++i) {
            int c = t + 256 * i;
            int r = c >> 3, col = (c & 7) * 8;
            *(uint4*)&Ks[r * 72 + col] = kreg[i];
            int dd = c >> 4, kvc = (c & 15) * 8;
            *(uint4*)&Vs[dd * 136 + kvc] = vreg[i];
        }
        __syncthreads();

        if (kt < ktmax) {   // prefetch next tile; overlaps compute
            #pragma unroll
            for (int i = 0; i < 4; ++i) {
                int c = t + 256 * i;
                int r = c >> 3, col = (c & 7) * 8;
                kreg[i] = *(const uint4*)&Kbase[(size_t)((kt + 1) * 128 + r) * 64 + col];
                int dd = c >> 4, kvc = (c & 15) * 8;
                vreg[i] = *(const uint4*)&Vbase[(size_t)dd * 2048 + (kt + 1) * 128 + kvc];
            }
        }

        // S^T = K Q^T for BOTH strips; K fragment read once
        f32x4 accs[2][8];
        #pragma unroll
        for (int s = 0; s < 2; ++s)
            #pragma unroll
            for (int ni = 0; ni < 8; ++ni) accs[s][ni] = z;
        #pragma unroll
        for (int kk = 0; kk < 2; ++kk)
            #pragma unroll
            for (int ni = 0; ni < 8; ++ni) {
                bf16x8 bk = *(const bf16x8*)&Ks[(ni * 16 + m16) * 72 + kk * 32 + quad * 8];
                accs[0][ni] = MFMA16(bk, fq[0][kk], accs[0][ni]);
                accs[1][ni] = MFMA16(bk, fq[1][kk], accs[1][ni]);
            }

        // V fragments to registers once per tile (shared by both strips)
        bf16x8 bvr[4][4];
        #pragma unroll
        for (int kk = 0; kk < 4; ++kk)
            #pragma unroll
            for (int nd = 0; nd < 4; ++nd)
                bvr[kk][nd] = *(const bf16x8*)&Vs[(nd * 16 + m16) * 136 + kk * 32 + quad * 8];

        const bool diag = (kt == ktmax);
        #pragma unroll
        for (int s = 0; s < 2; ++s) {
            // p = exp2(s^T) -> Ps: lane owns q-row m16, 4-consecutive kv per acc
            const int qg = q0 + s * 64 + w * 16 + m16;
            #pragma unroll
            for (int ni = 0; ni < 8; ++ni) {
                union { __bf16 b[4]; uint2 u; } pk;
                #pragma unroll
                for (int v = 0; v < 4; ++v) {
                    float sc = accs[s][ni][v];
                    if (diag && (kt * 128 + ni * 16 + quad * 4 + v > qg)) sc = -30000.0f;
                    pk.b[v] = (__bf16)__builtin_amdgcn_exp2f(sc);
                }
                *(uint2*)&Ps[pr + ni * 16 + quad * 4] = pk.u;
            }

            // O += P V ; l += P * ones   (in-wave DS ordering: same rows)
            #pragma unroll
            for (int kk = 0; kk < 4; ++kk) {
                bf16x8 ap = *(const bf16x8*)&Ps[pr + kk * 32 + quad * 8];
                #pragma unroll
                for (int nd = 0; nd < 4; ++nd)
                    acco[s][nd] = MFMA16(ap, bvr[kk][nd], acco[s][nd]);
                accl[s] = MFMA16(ap, ones, accl[s]);
            }
        }
    }

    // write O back into Ql ([bh][t][64] layout); l sits in accl C-layout
    #pragma unroll
    for (int s = 0; s < 2; ++s)
        #pragma unroll
        for (int v = 0; v < 4; ++v) {
            int qg = q0 + s * 64 + w * 16 + quad * 4 + v;
            float inv = 1.0f / fmaxf(accl[s][v], 1e-30f);
            #pragma unroll
            for (int nd = 0; nd < 4; ++nd)
                Ql[((size_t)bh * 2048 + qg) * 64 + nd * 16 + m16] = f2b(acco[s][nd][v] * inv);
        }
}

// ------- proj GEMM: Y (in Ql layout [bh][t][64]) x WpT[1024,1024]^T + bias -
__global__ __launch_bounds__(256) void k_gemm_proj(
    const u16* __restrict__ Yl, const u16* __restrict__ Bt, const u16* __restrict__ bias,
    const int* __restrict__ flag, void* __restrict__ Out)
{
    constexpr int K = 1024;
    __shared__ __align__(16) u16 As[128 * 64];
    __shared__ __align__(16) u16 Bs[128 * 64];
    const int f32m = *flag;
    const int t = threadIdx.x;
    const int lane = t & 63, w = t >> 6;
    const int quad = lane >> 4, m16 = lane & 15;
    const int wm = (w >> 1) * 64, wn = (w & 1) * 64;
    const int m0 = blockIdx.x * 128, n0 = blockIdx.y * 128;
    const int bb = m0 >> 11, t0 = m0 & 2047;   // block-uniform (128 | 2048)
    const int lr = lane >> 3;
    const int lc = (lane & 7) * 8;

    const f32x4 z = {0.f, 0.f, 0.f, 0.f};
    f32x4 acc[4][4];
    #pragma unroll
    for (int mi = 0; mi < 4; ++mi)
        #pragma unroll
        for (int ni = 0; ni < 4; ++ni) acc[mi][ni] = z;

    for (int k0 = 0; k0 < K; k0 += 64) {
        const int h = k0 >> 6;
        const u16* Abase = Yl + ((size_t)(bb * 16 + h) * 2048 + t0) * 64;
        __syncthreads();
        #pragma unroll
        for (int i = 0; i < 4; ++i) {
            const int chunk = w * 4 + i;               // wave-uniform
            gload_lds16(&Abase[chunk * 512 + lane * 8], &As[chunk * 512]);
            gload_lds16(&Bt[(size_t)(n0 + chunk * 8 + lr) * K + k0 + lc], &Bs[chunk * 512]);
        }
        __syncthreads();
        #pragma unroll
        for (int kk = 0; kk < 2; ++kk) {
            bf16x8 af[4], bfr[4];
            #pragma unroll
            for (int mi = 0; mi < 4; ++mi)
                af[mi] = *(const bf16x8*)&As[(wm + mi * 16 + m16) * 64 + kk * 32 + quad * 8];
            #pragma unroll
            for (int ni = 0; ni < 4; ++ni)
                bfr[ni] = *(const bf16x8*)&Bs[(wn + ni * 16 + m16) * 64 + kk * 32 + quad * 8];
            #pragma unroll
            for (int mi = 0; mi < 4; ++mi)
                #pragma unroll
                for (int ni = 0; ni < 4; ++ni)
                    acc[mi][ni] = MFMA16(af[mi], bfr[ni], acc[mi][ni]);
        }
    }

    #pragma unroll
    for (int mi = 0; mi < 4; ++mi) {
        #pragma unroll
        for (int ni = 0; ni < 4; ++ni) {
            int gn = n0 + wn + ni * 16 + m16;
            float bv = b2f(bias[gn]);
            #pragma unroll
            for (int v = 0; v < 4; ++v) {
                int gm = m0 + wm + mi * 16 + quad * 4 + v;
                float val = acc[mi][ni][v] + bv;
                if (f32m) ((float*)Out)[(size_t)gm * 1024 + gn] = val;
                else      ((u16*)Out)[(size_t)gm * 1024 + gn] = f2b(val);
            }
        }
    }
}

extern "C" void kernel_launch(void* const* d_in, const int* in_sizes, int n_in,
                              void* d_out, int out_size, void* d_ws, size_t ws_size,
                              hipStream_t stream)
{
    (void)in_sizes; (void)n_in; (void)out_size; (void)ws_size;
    const void* x  = d_in[0];   // [8192,1024]  f32 or bf16
    const void* Wa = d_in[1];   // [1024,3072]
    const void* ba = d_in[2];   // [3072]
    const void* Wp = d_in[3];   // [1024,1024]
    const void* bp = d_in[4];   // [1024]
    char* ws = (char*)d_ws;

    // ws: Q/O 16M @0 | K 16M @16M | V 16M @32M | WpT 2M @48M | flag/bpc/bac @50M
    u16* Ql  = (u16*)(ws + 0);
    u16* Kl  = (u16*)(ws + 16777216);
    u16* Vt  = (u16*)(ws + 33554432);
    u16* WpT = (u16*)(ws + 50331648);
    int* flag = (int*)(ws + 52428800);
    u16* bpc  = (u16*)(ws + 52428800 + 256);
    u16* bac  = (u16*)(ws + 52428800 + 256 + 2048);
    // d_out doubles as scratch until proj:
    //   WaT 6M @0 | Abf (bf16 x) 16M @6M (written only in f32 mode, where
    //   out_size = 33.5M; in bf16 mode Abf is never touched and A = x).
    u16* WaT = (u16*)d_out;
    u16* Abf = (u16*)((char*)d_out + 6291456);

    k_detect<<<1, 256, 0, stream>>>((const u16*)x, flag);
    k_cvt_bias<<<1, 256, 0, stream>>>(ba, bp, flag, bac, bpc);
    k_cvt_x<<<4096, 256, 0, stream>>>((const float*)x, flag, Abf);
    k_transpose<<<dim3(48, 16), 256, 0, stream>>>(Wa, WaT, 1024, 3072, flag);
    k_transpose<<<dim3(16, 16), 256, 0, stream>>>(Wp, WpT, 1024, 1024, flag);
    k_gemm_qkv<<<dim3(64, 24), 256, 0, stream>>>(x, Abf, WaT, bac, flag, Ql, Kl, Vt);
    k_attn<<<1024, 256, 0, stream>>>(Ql, Kl, Vt);
    k_gemm_proj<<<dim3(64, 8), 256, 0, stream>>>(Ql, WpT, bpc, flag, d_out);
}

// Round 3
// 340.190 us; speedup vs baseline: 1.0899x; 1.0899x over previous
//
#include <hip/hip_runtime.h>

typedef unsigned short u16;
typedef unsigned int u32;
typedef __bf16 bf16x8 __attribute__((ext_vector_type(8)));
typedef float f32x4 __attribute__((ext_vector_type(4)));

#define MFMA16(a,b,c) __builtin_amdgcn_mfma_f32_16x16x32_bf16((a),(b),(c),0,0,0)

__device__ __forceinline__ float b2f(u16 u) {
    u32 v = ((u32)u) << 16;
    return __builtin_bit_cast(float, v);
}
__device__ __forceinline__ u16 f2b(float f) {
    u32 u = __builtin_bit_cast(u32, f);
    u = u + 0x7FFFu + ((u >> 16) & 1u);   // RNE
    return (u16)(u >> 16);
}

// async global->LDS, 16B per lane. LDS dest is wave-uniform base + lane*16.
__device__ __forceinline__ void gload_lds16(const u16* g, u16* l) {
    __builtin_amdgcn_global_load_lds(
        (__attribute__((address_space(1))) void*)g,
        (__attribute__((address_space(3))) void*)l, 16, 0, 0);
}

// load 8 contiguous elements at element-offset `off`, as 8 bf16 (uint4).
__device__ __forceinline__ uint4 load8_bf16(const void* base, size_t off, int f32m) {
    if (f32m) {
        const float* p = (const float*)base + off;
        float4 a = *(const float4*)p;
        float4 b = *(const float4*)(p + 4);
        union { u16 u[8]; uint4 v; } t;
        t.u[0] = f2b(a.x); t.u[1] = f2b(a.y); t.u[2] = f2b(a.z); t.u[3] = f2b(a.w);
        t.u[4] = f2b(b.x); t.u[5] = f2b(b.y); t.u[6] = f2b(b.z); t.u[7] = f2b(b.w);
        return t.v;
    }
    return *(const uint4*)((const u16*)base + off);
}

// ---- dtype detector: even-indexed u16s of f32 data are random mantissa bits
__global__ __launch_bounds__(256) void k_detect(const u16* __restrict__ x, int* flag) {
    __shared__ int c;
    if (threadIdx.x == 0) c = 0;
    __syncthreads();
    int my = 0;
    #pragma unroll
    for (int j = 0; j < 16; ++j) {
        u16 v = x[2 * (threadIdx.x + 256 * j)];
        if (((v >> 7) & 0xFF) >= 0x90) ++my;
    }
    atomicAdd(&c, my);
    __syncthreads();
    if (threadIdx.x == 0) *flag = (c > 64) ? 1 : 0;
}

__global__ __launch_bounds__(256) void k_cvt_bias(
    const void* __restrict__ ba, const void* __restrict__ bp,
    const int* __restrict__ flag, u16* __restrict__ bac, u16* __restrict__ bpc)
{
    const int f32m = *flag;
    const int t = threadIdx.x;
    #pragma unroll
    for (int j = 0; j < 12; ++j) {
        int i = t + 256 * j;
        if (i < 3072) bac[i] = f32m ? f2b(((const float*)ba)[i]) : ((const u16*)ba)[i];
    }
    #pragma unroll
    for (int j = 0; j < 4; ++j) {
        int i = t + 256 * j;
        if (i < 1024) bpc[i] = f32m ? f2b(((const float*)bp)[i]) : ((const u16*)bp)[i];
    }
}

// ---- one-time x f32->bf16 conversion (f32 mode only; bf16 mode uses x directly)
__global__ __launch_bounds__(256) void k_cvt_x(
    const float* __restrict__ x, const int* __restrict__ flag, u16* __restrict__ out)
{
    if (!*flag) return;
    size_t i = ((size_t)blockIdx.x * 256 + threadIdx.x) * 8;
    float4 a = *(const float4*)(x + i);
    float4 b = *(const float4*)(x + i + 4);
    union { u16 u[8]; uint4 v; } t;
    t.u[0] = f2b(a.x); t.u[1] = f2b(a.y); t.u[2] = f2b(a.z); t.u[3] = f2b(a.w);
    t.u[4] = f2b(b.x); t.u[5] = f2b(b.y); t.u[6] = f2b(b.z); t.u[7] = f2b(b.w);
    *(uint4*)(out + i) = t.v;
}

// ---------------- transpose+convert: src[R][Cc] -> dst[Cc][R] bf16 ---------
__global__ __launch_bounds__(256) void k_transpose(
    const void* __restrict__ src, u16* __restrict__ dst, int R, int Cc,
    const int* __restrict__ flag)
{
    __shared__ u16 tile[64 * 72];
    const int f32m = *flag;
    const int t = threadIdx.x;
    const int c0 = blockIdx.x * 64, r0 = blockIdx.y * 64;
    #pragma unroll
    for (int i = 0; i < 2; ++i) {
        int ch = t + 256 * i;            // 512 chunks of 8
        int r = ch >> 3, c8 = (ch & 7) * 8;
        *(uint4*)&tile[r * 72 + c8] =
            load8_bf16(src, (size_t)(r0 + r) * Cc + c0 + c8, f32m);
    }
    __syncthreads();
    #pragma unroll
    for (int i = 0; i < 2; ++i) {
        int ch = t + 256 * i;
        int r = ch >> 3, c8 = (ch & 7) * 8;
        union { u16 u[8]; uint4 v; } tmp;
        #pragma unroll
        for (int j = 0; j < 8; ++j) tmp.u[j] = tile[(c8 + j) * 72 + r];
        *(uint4*)&dst[(size_t)(c0 + r) * R + r0 + c8] = tmp.v;
    }
}

// ---------------- QKV GEMM: A[8192,1024] x Bt[3072,1024]^T + bias ----------
// m97 structure: linear [128][64] bf16 LDS tiles, global_load_lds width-16
// staging, 2 barriers per K-step.
__global__ __launch_bounds__(256) void k_gemm_qkv(
    const void* __restrict__ x, const u16* __restrict__ Abf,
    const u16* __restrict__ Bt, const u16* __restrict__ bias,
    const int* __restrict__ flag,
    u16* __restrict__ Ql, u16* __restrict__ Kl, u16* __restrict__ Vt)
{
    constexpr int K = 1024;
    __shared__ __align__(16) u16 As[128 * 64];
    __shared__ __align__(16) u16 Bs[128 * 64];
    const int t = threadIdx.x;
    const int lane = t & 63, w = t >> 6;
    const int quad = lane >> 4, m16 = lane & 15;
    const int wm = (w >> 1) * 64, wn = (w & 1) * 64;
    const int m0 = blockIdx.x * 128, n0 = blockIdx.y * 128;
    const int lr = lane >> 3;            // row within 8-row chunk
    const int lc = (lane & 7) * 8;       // elem col within 64
    const u16* A = (*flag) ? Abf : (const u16*)x;

    const f32x4 z = {0.f, 0.f, 0.f, 0.f};
    f32x4 acc[4][4];
    #pragma unroll
    for (int mi = 0; mi < 4; ++mi)
        #pragma unroll
        for (int ni = 0; ni < 4; ++ni) acc[mi][ni] = z;

    for (int k0 = 0; k0 < K; k0 += 64) {
        __syncthreads();                 // previous compute done reading LDS
        #pragma unroll
        for (int i = 0; i < 4; ++i) {
            const int chunk = w * 4 + i;               // wave-uniform
            const int row = chunk * 8 + lr;
            gload_lds16(&A [(size_t)(m0 + row) * K + k0 + lc], &As[chunk * 512]);
            gload_lds16(&Bt[(size_t)(n0 + row) * K + k0 + lc], &Bs[chunk * 512]);
        }
        __syncthreads();                 // compiler drains vmcnt(0) here
        #pragma unroll
        for (int kk = 0; kk < 2; ++kk) {
            bf16x8 af[4], bfr[4];
            #pragma unroll
            for (int mi = 0; mi < 4; ++mi)
                af[mi] = *(const bf16x8*)&As[(wm + mi * 16 + m16) * 64 + kk * 32 + quad * 8];
            #pragma unroll
            for (int ni = 0; ni < 4; ++ni)
                bfr[ni] = *(const bf16x8*)&Bs[(wn + ni * 16 + m16) * 64 + kk * 32 + quad * 8];
            #pragma unroll
            for (int mi = 0; mi < 4; ++mi)
                #pragma unroll
                for (int ni = 0; ni < 4; ++ni)
                    acc[mi][ni] = MFMA16(af[mi], bfr[ni], acc[mi][ni]);
        }
    }

    const int sec = n0 >> 10;  // 0=Q,1=K,2=V — uniform per block (128 | 1024)
    const float qscale = (sec == 0) ? 0.18033688011112042f : 1.0f;  // 0.125*log2e
    #pragma unroll
    for (int mi = 0; mi < 4; ++mi) {
        #pragma unroll
        for (int ni = 0; ni < 4; ++ni) {
            int gn = n0 + wn + ni * 16 + m16;
            int sn = gn & 1023;
            int h = sn >> 6, d = sn & 63;
            float bv = b2f(bias[gn]);
            #pragma unroll
            for (int v = 0; v < 4; ++v) {
                int gm = m0 + wm + mi * 16 + quad * 4 + v;
                int bb = gm >> 11, tt = gm & 2047;
                u16 o = f2b((acc[mi][ni][v] + bv) * qscale);
                size_t bh = (size_t)(bb * 16 + h);
                if (sec == 0)      Ql[(bh * 2048 + tt) * 64 + d] = o;
                else if (sec == 1) Kl[(bh * 2048 + tt) * 64 + d] = o;
                else               Vt[(bh * 64 + d) * 2048 + tt] = o;
            }
        }
    }
}

// ---------------- flash attention: block = (128 q rows, one (b,h)) ---------
// Swapped QK^T (accs = mfma(K,Q) = S^T): lane holds 4-consecutive-kv runs,
// so the P store is 8x ds_write_b64 of compiler-packed bf16 per strip
// instead of 32 scalar ds_write_b16 + hand packing.
// Strips processed SEQUENTIALLY and V read from LDS in the PV loop: keeps
// peak VGPR under the 128 allocation cliff (round-2 lesson: hoisting both
// strips + V to registers -> 144 VGPR -> occupancy halved -> 22% slower).
__global__ __launch_bounds__(256) void k_attn(
    u16* __restrict__ Ql, const u16* __restrict__ Kl, const u16* __restrict__ Vt)
{
    __shared__ u16 Ks[128 * 72];
    __shared__ u16 Vs[64 * 136];
    __shared__ u16 Ps[64 * 136];
    const int t = threadIdx.x;
    const int lane = t & 63, w = t >> 6;
    const int quad = lane >> 4, m16 = lane & 15;
    const int qb = 15 - (blockIdx.x >> 6);
    const int bh = blockIdx.x & 63;
    const int q0 = qb * 128;

    // Q fragments for both strips, registers for the whole block
    bf16x8 fq[2][2];
    #pragma unroll
    for (int s = 0; s < 2; ++s) {
        const u16* Qp = Ql + ((size_t)bh * 2048 + q0 + s * 64 + w * 16 + m16) * 64;
        fq[s][0] = *(const bf16x8*)&Qp[quad * 8];
        fq[s][1] = *(const bf16x8*)&Qp[32 + quad * 8];
    }

    const f32x4 z = {0.f, 0.f, 0.f, 0.f};
    f32x4 acco[2][4] = {{z, z, z, z}, {z, z, z, z}};
    f32x4 accl[2] = {z, z};
    bf16x8 ones;
    #pragma unroll
    for (int j = 0; j < 8; ++j) ones[j] = (__bf16)1.0f;

    const int ktmax = qb;
    const u16* Kbase = Kl + (size_t)bh * 2048 * 64;
    const u16* Vbase = Vt + (size_t)bh * 64 * 2048;

    uint4 kreg[4], vreg[4];
    #pragma unroll
    for (int i = 0; i < 4; ++i) {
        int c = t + 256 * i;
        int r = c >> 3, col = (c & 7) * 8;
        kreg[i] = *(const uint4*)&Kbase[(size_t)r * 64 + col];          // kt=0
        int dd = c >> 4, kvc = (c & 15) * 8;
        vreg[i] = *(const uint4*)&Vbase[(size_t)dd * 2048 + kvc];       // kt=0
    }

    const int pr = (w * 16 + m16) * 136;   // wave-private Ps row (u16 units)

    for (int kt = 0; kt <= ktmax; ++kt) {
        __syncthreads();
        #pragma unroll
        for (int i = 0; i < 4; ++i) {
            int c = t + 256 * i;
            int r = c >> 3, col = (c & 7) * 8;
            *(uint4*)&Ks[r * 72 + col] = kreg[i];
            int dd = c >> 4, kvc = (c & 15) * 8;
            *(uint4*)&Vs[dd * 136 + kvc] = vreg[i];
        }
        __syncthreads();

        if (kt < ktmax) {   // prefetch next tile; overlaps compute
            #pragma unroll
            for (int i = 0; i < 4; ++i) {
                int c = t + 256 * i;
                int r = c >> 3, col = (c & 7) * 8;
                kreg[i] = *(const uint4*)&Kbase[(size_t)((kt + 1) * 128 + r) * 64 + col];
                int dd = c >> 4, kvc = (c & 15) * 8;
                vreg[i] = *(const uint4*)&Vbase[(size_t)dd * 2048 + (kt + 1) * 128 + kvc];
            }
        }

        const bool diag = (kt == ktmax);
        #pragma unroll
        for (int s = 0; s < 2; ++s) {
            // S^T = K Q^T  (lane: q = m16, kv = ni*16 + quad*4 + v)
            f32x4 accs[8] = {z, z, z, z, z, z, z, z};
            #pragma unroll
            for (int kk = 0; kk < 2; ++kk)
                #pragma unroll
                for (int ni = 0; ni < 8; ++ni) {
                    bf16x8 bk = *(const bf16x8*)&Ks[(ni * 16 + m16) * 72 + kk * 32 + quad * 8];
                    accs[ni] = MFMA16(bk, fq[s][kk], accs[ni]);
                }

            // p = exp2(s^T) -> Ps[q][kv], packed ds_write_b64
            const int qg = q0 + s * 64 + w * 16 + m16;
            #pragma unroll
            for (int ni = 0; ni < 8; ++ni) {
                union { __bf16 b[4]; uint2 u; } pk;
                #pragma unroll
                for (int v = 0; v < 4; ++v) {
                    float sc = accs[ni][v];
                    if (diag && (kt * 128 + ni * 16 + quad * 4 + v > qg)) sc = -30000.0f;
                    pk.b[v] = (__bf16)__builtin_amdgcn_exp2f(sc);
                }
                *(uint2*)&Ps[pr + ni * 16 + quad * 4] = pk.u;
            }

            // O += P V ; l += P * ones   (in-wave DS ordering: same rows)
            #pragma unroll
            for (int kk = 0; kk < 4; ++kk) {
                bf16x8 ap = *(const bf16x8*)&Ps[pr + kk * 32 + quad * 8];
                #pragma unroll
                for (int nd = 0; nd < 4; ++nd) {
                    bf16x8 bv = *(const bf16x8*)&Vs[(nd * 16 + m16) * 136 + kk * 32 + quad * 8];
                    acco[s][nd] = MFMA16(ap, bv, acco[s][nd]);
                }
                accl[s] = MFMA16(ap, ones, accl[s]);
            }
        }
    }

    // write O back into Ql ([bh][t][64] layout); l sits in accl C-layout
    #pragma unroll
    for (int s = 0; s < 2; ++s)
        #pragma unroll
        for (int v = 0; v < 4; ++v) {
            int qg = q0 + s * 64 + w * 16 + quad * 4 + v;
            float inv = 1.0f / fmaxf(accl[s][v], 1e-30f);
            #pragma unroll
            for (int nd = 0; nd < 4; ++nd)
                Ql[((size_t)bh * 2048 + qg) * 64 + nd * 16 + m16] = f2b(acco[s][nd][v] * inv);
        }
}

// ------- proj GEMM: Y (in Ql layout [bh][t][64]) x WpT[1024,1024]^T + bias -
__global__ __launch_bounds__(256) void k_gemm_proj(
    const u16* __restrict__ Yl, const u16* __restrict__ Bt, const u16* __restrict__ bias,
    const int* __restrict__ flag, void* __restrict__ Out)
{
    constexpr int K = 1024;
    __shared__ __align__(16) u16 As[128 * 64];
    __shared__ __align__(16) u16 Bs[128 * 64];
    const int f32m = *flag;
    const int t = threadIdx.x;
    const int lane = t & 63, w = t >> 6;
    const int quad = lane >> 4, m16 = lane & 15;
    const int wm = (w >> 1) * 64, wn = (w & 1) * 64;
    const int m0 = blockIdx.x * 128, n0 = blockIdx.y * 128;
    const int bb = m0 >> 11, t0 = m0 & 2047;   // block-uniform (128 | 2048)
    const int lr = lane >> 3;
    const int lc = (lane & 7) * 8;

    const f32x4 z = {0.f, 0.f, 0.f, 0.f};
    f32x4 acc[4][4];
    #pragma unroll
    for (int mi = 0; mi < 4; ++mi)
        #pragma unroll
        for (int ni = 0; ni < 4; ++ni) acc[mi][ni] = z;

    for (int k0 = 0; k0 < K; k0 += 64) {
        const int h = k0 >> 6;
        const u16* Abase = Yl + ((size_t)(bb * 16 + h) * 2048 + t0) * 64;
        __syncthreads();
        #pragma unroll
        for (int i = 0; i < 4; ++i) {
            const int chunk = w * 4 + i;               // wave-uniform
            gload_lds16(&Abase[chunk * 512 + lane * 8], &As[chunk * 512]);
            gload_lds16(&Bt[(size_t)(n0 + chunk * 8 + lr) * K + k0 + lc], &Bs[chunk * 512]);
        }
        __syncthreads();
        #pragma unroll
        for (int kk = 0; kk < 2; ++kk) {
            bf16x8 af[4], bfr[4];
            #pragma unroll
            for (int mi = 0; mi < 4; ++mi)
                af[mi] = *(const bf16x8*)&As[(wm + mi * 16 + m16) * 64 + kk * 32 + quad * 8];
            #pragma unroll
            for (int ni = 0; ni < 4; ++ni)
                bfr[ni] = *(const bf16x8*)&Bs[(wn + ni * 16 + m16) * 64 + kk * 32 + quad * 8];
            #pragma unroll
            for (int mi = 0; mi < 4; ++mi)
                #pragma unroll
                for (int ni = 0; ni < 4; ++ni)
                    acc[mi][ni] = MFMA16(af[mi], bfr[ni], acc[mi][ni]);
        }
    }

    #pragma unroll
    for (int mi = 0; mi < 4; ++mi) {
        #pragma unroll
        for (int ni = 0; ni < 4; ++ni) {
            int gn = n0 + wn + ni * 16 + m16;
            float bv = b2f(bias[gn]);
            #pragma unroll
            for (int v = 0; v < 4; ++v) {
                int gm = m0 + wm + mi * 16 + quad * 4 + v;
                float val = acc[mi][ni][v] + bv;
                if (f32m) ((float*)Out)[(size_t)gm * 1024 + gn] = val;
                else      ((u16*)Out)[(size_t)gm * 1024 + gn] = f2b(val);
            }
        }
    }
}

extern "C" void kernel_launch(void* const* d_in, const int* in_sizes, int n_in,
                              void* d_out, int out_size, void* d_ws, size_t ws_size,
                              hipStream_t stream)
{
    (void)in_sizes; (void)n_in; (void)out_size; (void)ws_size;
    const void* x  = d_in[0];   // [8192,1024]  f32 or bf16
    const void* Wa = d_in[1];   // [1024,3072]
    const void* ba = d_in[2];   // [3072]
    const void* Wp = d_in[3];   // [1024,1024]
    const void* bp = d_in[4];   // [1024]
    char* ws = (char*)d_ws;

    // ws: Q/O 16M @0 | K 16M @16M | V 16M @32M | WpT 2M @48M | flag/bpc/bac @50M
    u16* Ql  = (u16*)(ws + 0);
    u16* Kl  = (u16*)(ws + 16777216);
    u16* Vt  = (u16*)(ws + 33554432);
    u16* WpT = (u16*)(ws + 50331648);
    int* flag = (int*)(ws + 52428800);
    u16* bpc  = (u16*)(ws + 52428800 + 256);
    u16* bac  = (u16*)(ws + 52428800 + 256 + 2048);
    // d_out doubles as scratch until proj:
    //   WaT 6M @0 | Abf (bf16 x) 16M @6M (written only in f32 mode, where
    //   out_size = 33.5M; in bf16 mode Abf is never touched and A = x).
    u16* WaT = (u16*)d_out;
    u16* Abf = (u16*)((char*)d_out + 6291456);

    k_detect<<<1, 256, 0, stream>>>((const u16*)x, flag);
    k_cvt_bias<<<1, 256, 0, stream>>>(ba, bp, flag, bac, bpc);
    k_cvt_x<<<4096, 256, 0, stream>>>((const float*)x, flag, Abf);
    k_transpose<<<dim3(48, 16), 256, 0, stream>>>(Wa, WaT, 1024, 3072, flag);
    k_transpose<<<dim3(16, 16), 256, 0, stream>>>(Wp, WpT, 1024, 1024, flag);
    k_gemm_qkv<<<dim3(64, 24), 256, 0, stream>>>(x, Abf, WaT, bac, flag, Ql, Kl, Vt);
    k_attn<<<1024, 256, 0, stream>>>(Ql, Kl, Vt);
    k_gemm_proj<<<dim3(64, 8), 256, 0, stream>>>(Ql, WpT, bpc, flag, d_out);
}

// Round 4
// 336.889 us; speedup vs baseline: 1.1005x; 1.0098x over previous
//
#include <hip/hip_runtime.h>

typedef unsigned short u16;
typedef unsigned int u32;
typedef __bf16 bf16x8 __attribute__((ext_vector_type(8)));
typedef short s16x4 __attribute__((ext_vector_type(4)));
typedef float f32x4 __attribute__((ext_vector_type(4)));

#define MFMA16(a,b,c) __builtin_amdgcn_mfma_f32_16x16x32_bf16((a),(b),(c),0,0,0)

// K=16 bf16 MFMA (v_mfma_f32_16x16x16_bf16): A/B = 4 bf16 (2 VGPR), C/D = 4 f32.
#if defined(__has_builtin)
#if __has_builtin(__builtin_amdgcn_mfma_f32_16x16x16bf16_1k)
#define MFMA1K(a,b,c) __builtin_amdgcn_mfma_f32_16x16x16bf16_1k((a),(b),(c),0,0,0)
#endif
#endif
#ifndef MFMA1K
__device__ __forceinline__ f32x4 mfma1k_asm(s16x4 a, s16x4 b, f32x4 c) {
    f32x4 d;
    asm volatile("v_mfma_f32_16x16x16_bf16 %0, %1, %2, %3"
                 : "=v"(d) : "v"(a), "v"(b), "0"(c));
    return d;
}
#define MFMA1K(a,b,c) mfma1k_asm((a),(b),(c))
#endif

__device__ __forceinline__ float b2f(u16 u) {
    u32 v = ((u32)u) << 16;
    return __builtin_bit_cast(float, v);
}
__device__ __forceinline__ u16 f2b(float f) {
    u32 u = __builtin_bit_cast(u32, f);
    u = u + 0x7FFFu + ((u >> 16) & 1u);   // RNE
    return (u16)(u >> 16);
}

// async global->LDS, 16B per lane. LDS dest is wave-uniform base + lane*16.
__device__ __forceinline__ void gload_lds16(const u16* g, u16* l) {
    __builtin_amdgcn_global_load_lds(
        (__attribute__((address_space(1))) void*)g,
        (__attribute__((address_space(3))) void*)l, 16, 0, 0);
}

// load 8 contiguous elements at element-offset `off`, as 8 bf16 (uint4).
__device__ __forceinline__ uint4 load8_bf16(const void* base, size_t off, int f32m) {
    if (f32m) {
        const float* p = (const float*)base + off;
        float4 a = *(const float4*)p;
        float4 b = *(const float4*)(p + 4);
        union { u16 u[8]; uint4 v; } t;
        t.u[0] = f2b(a.x); t.u[1] = f2b(a.y); t.u[2] = f2b(a.z); t.u[3] = f2b(a.w);
        t.u[4] = f2b(b.x); t.u[5] = f2b(b.y); t.u[6] = f2b(b.z); t.u[7] = f2b(b.w);
        return t.v;
    }
    return *(const uint4*)((const u16*)base + off);
}

// ---- dtype detector: even-indexed u16s of f32 data are random mantissa bits
__global__ __launch_bounds__(256) void k_detect(const u16* __restrict__ x, int* flag) {
    __shared__ int c;
    if (threadIdx.x == 0) c = 0;
    __syncthreads();
    int my = 0;
    #pragma unroll
    for (int j = 0; j < 16; ++j) {
        u16 v = x[2 * (threadIdx.x + 256 * j)];
        if (((v >> 7) & 0xFF) >= 0x90) ++my;
    }
    atomicAdd(&c, my);
    __syncthreads();
    if (threadIdx.x == 0) *flag = (c > 64) ? 1 : 0;
}

__global__ __launch_bounds__(256) void k_cvt_bias(
    const void* __restrict__ ba, const void* __restrict__ bp,
    const int* __restrict__ flag, u16* __restrict__ bac, u16* __restrict__ bpc)
{
    const int f32m = *flag;
    const int t = threadIdx.x;
    #pragma unroll
    for (int j = 0; j < 12; ++j) {
        int i = t + 256 * j;
        if (i < 3072) bac[i] = f32m ? f2b(((const float*)ba)[i]) : ((const u16*)ba)[i];
    }
    #pragma unroll
    for (int j = 0; j < 4; ++j) {
        int i = t + 256 * j;
        if (i < 1024) bpc[i] = f32m ? f2b(((const float*)bp)[i]) : ((const u16*)bp)[i];
    }
}

// ---- one-time x f32->bf16 conversion (f32 mode only; bf16 mode uses x directly)
__global__ __launch_bounds__(256) void k_cvt_x(
    const float* __restrict__ x, const int* __restrict__ flag, u16* __restrict__ out)
{
    if (!*flag) return;
    size_t i = ((size_t)blockIdx.x * 256 + threadIdx.x) * 8;
    float4 a = *(const float4*)(x + i);
    float4 b = *(const float4*)(x + i + 4);
    union { u16 u[8]; uint4 v; } t;
    t.u[0] = f2b(a.x); t.u[1] = f2b(a.y); t.u[2] = f2b(a.z); t.u[3] = f2b(a.w);
    t.u[4] = f2b(b.x); t.u[5] = f2b(b.y); t.u[6] = f2b(b.z); t.u[7] = f2b(b.w);
    *(uint4*)(out + i) = t.v;
}

// ---------------- transpose+convert: src[R][Cc] -> dst[Cc][R] bf16 ---------
__global__ __launch_bounds__(256) void k_transpose(
    const void* __restrict__ src, u16* __restrict__ dst, int R, int Cc,
    const int* __restrict__ flag)
{
    __shared__ u16 tile[64 * 72];
    const int f32m = *flag;
    const int t = threadIdx.x;
    const int c0 = blockIdx.x * 64, r0 = blockIdx.y * 64;
    #pragma unroll
    for (int i = 0; i < 2; ++i) {
        int ch = t + 256 * i;            // 512 chunks of 8
        int r = ch >> 3, c8 = (ch & 7) * 8;
        *(uint4*)&tile[r * 72 + c8] =
            load8_bf16(src, (size_t)(r0 + r) * Cc + c0 + c8, f32m);
    }
    __syncthreads();
    #pragma unroll
    for (int i = 0; i < 2; ++i) {
        int ch = t + 256 * i;
        int r = ch >> 3, c8 = (ch & 7) * 8;
        union { u16 u[8]; uint4 v; } tmp;
        #pragma unroll
        for (int j = 0; j < 8; ++j) tmp.u[j] = tile[(c8 + j) * 72 + r];
        *(uint4*)&dst[(size_t)(c0 + r) * R + r0 + c8] = tmp.v;
    }
}

// ---------------- QKV GEMM: A[8192,1024] x Bt[3072,1024]^T + bias ----------
// m97 structure: linear [128][64] bf16 LDS tiles, global_load_lds width-16
// staging, 2 barriers per K-step.
__global__ __launch_bounds__(256) void k_gemm_qkv(
    const void* __restrict__ x, const u16* __restrict__ Abf,
    const u16* __restrict__ Bt, const u16* __restrict__ bias,
    const int* __restrict__ flag,
    u16* __restrict__ Ql, u16* __restrict__ Kl, u16* __restrict__ Vt)
{
    constexpr int K = 1024;
    __shared__ __align__(16) u16 As[128 * 64];
    __shared__ __align__(16) u16 Bs[128 * 64];
    const int t = threadIdx.x;
    const int lane = t & 63, w = t >> 6;
    const int quad = lane >> 4, m16 = lane & 15;
    const int wm = (w >> 1) * 64, wn = (w & 1) * 64;
    const int m0 = blockIdx.x * 128, n0 = blockIdx.y * 128;
    const int lr = lane >> 3;            // row within 8-row chunk
    const int lc = (lane & 7) * 8;       // elem col within 64
    const u16* A = (*flag) ? Abf : (const u16*)x;

    const f32x4 z = {0.f, 0.f, 0.f, 0.f};
    f32x4 acc[4][4];
    #pragma unroll
    for (int mi = 0; mi < 4; ++mi)
        #pragma unroll
        for (int ni = 0; ni < 4; ++ni) acc[mi][ni] = z;

    for (int k0 = 0; k0 < K; k0 += 64) {
        __syncthreads();                 // previous compute done reading LDS
        #pragma unroll
        for (int i = 0; i < 4; ++i) {
            const int chunk = w * 4 + i;               // wave-uniform
            const int row = chunk * 8 + lr;
            gload_lds16(&A [(size_t)(m0 + row) * K + k0 + lc], &As[chunk * 512]);
            gload_lds16(&Bt[(size_t)(n0 + row) * K + k0 + lc], &Bs[chunk * 512]);
        }
        __syncthreads();                 // compiler drains vmcnt(0) here
        #pragma unroll
        for (int kk = 0; kk < 2; ++kk) {
            bf16x8 af[4], bfr[4];
            #pragma unroll
            for (int mi = 0; mi < 4; ++mi)
                af[mi] = *(const bf16x8*)&As[(wm + mi * 16 + m16) * 64 + kk * 32 + quad * 8];
            #pragma unroll
            for (int ni = 0; ni < 4; ++ni)
                bfr[ni] = *(const bf16x8*)&Bs[(wn + ni * 16 + m16) * 64 + kk * 32 + quad * 8];
            #pragma unroll
            for (int mi = 0; mi < 4; ++mi)
                #pragma unroll
                for (int ni = 0; ni < 4; ++ni)
                    acc[mi][ni] = MFMA16(af[mi], bfr[ni], acc[mi][ni]);
        }
    }

    const int sec = n0 >> 10;  // 0=Q,1=K,2=V — uniform per block (128 | 1024)
    const float qscale = (sec == 0) ? 0.18033688011112042f : 1.0f;  // 0.125*log2e
    #pragma unroll
    for (int mi = 0; mi < 4; ++mi) {
        #pragma unroll
        for (int ni = 0; ni < 4; ++ni) {
            int gn = n0 + wn + ni * 16 + m16;
            int sn = gn & 1023;
            int h = sn >> 6, d = sn & 63;
            float bv = b2f(bias[gn]);
            #pragma unroll
            for (int v = 0; v < 4; ++v) {
                int gm = m0 + wm + mi * 16 + quad * 4 + v;
                int bb = gm >> 11, tt = gm & 2047;
                u16 o = f2b((acc[mi][ni][v] + bv) * qscale);
                size_t bh = (size_t)(bb * 16 + h);
                if (sec == 0)      Ql[(bh * 2048 + tt) * 64 + d] = o;
                else if (sec == 1) Kl[(bh * 2048 + tt) * 64 + d] = o;
                else               Vt[(bh * 64 + d) * 2048 + tt] = o;
            }
        }
    }
}

// ---------------- flash attention: block = (128 q rows, one (b,h)) ---------
// Swapped QK^T (accs = mfma(K,Q) = S^T): C-layout gives lane 4-consecutive-kv
// runs at q = lane&15 — exactly the B-fragment of the K=16 MFMA
// v_mfma_f32_16x16x16_bf16. So PV consumes P DIRECTLY FROM REGISTERS:
//   O^T[d][q] += mfma(A = V^T b64 frag from Vs, B = packed accs)
// No Ps buffer (LDS 53->38 KB: 4 blocks/CU instead of 3), no P LDS traffic,
// l = per-lane f32 sum + 2 shfl_xor, O^T epilogue stores coalesced uint2.
// Ks pad 72->80 u16: makes both staging b128 writes and bk b128 reads 2-way
// bank-aliased (free) instead of 8-way.
// Strips sequential; V from LDS (round-2 lesson: stay under 128 VGPR).
__global__ __launch_bounds__(256) void k_attn(
    u16* __restrict__ Ql, const u16* __restrict__ Kl, const u16* __restrict__ Vt)
{
    __shared__ u16 Ks[128 * 80];
    __shared__ u16 Vs[64 * 136];
    const int t = threadIdx.x;
    const int lane = t & 63, w = t >> 6;
    const int quad = lane >> 4, m16 = lane & 15;
    const int qb = 15 - (blockIdx.x >> 6);
    const int bh = blockIdx.x & 63;
    const int q0 = qb * 128;

    // Q fragments for both strips, registers for the whole block
    bf16x8 fq[2][2];
    #pragma unroll
    for (int s = 0; s < 2; ++s) {
        const u16* Qp = Ql + ((size_t)bh * 2048 + q0 + s * 64 + w * 16 + m16) * 64;
        fq[s][0] = *(const bf16x8*)&Qp[quad * 8];
        fq[s][1] = *(const bf16x8*)&Qp[32 + quad * 8];
    }

    const f32x4 z = {0.f, 0.f, 0.f, 0.f};
    f32x4 acco[2][4] = {{z, z, z, z}, {z, z, z, z}};   // O^T: q=m16, d=nd*16+quad*4+v
    float lsum[2] = {0.f, 0.f};

    const int ktmax = qb;
    const u16* Kbase = Kl + (size_t)bh * 2048 * 64;
    const u16* Vbase = Vt + (size_t)bh * 64 * 2048;

    uint4 kreg[4], vreg[4];
    #pragma unroll
    for (int i = 0; i < 4; ++i) {
        int c = t + 256 * i;
        int r = c >> 3, col = (c & 7) * 8;
        kreg[i] = *(const uint4*)&Kbase[(size_t)r * 64 + col];          // kt=0
        int dd = c >> 4, kvc = (c & 15) * 8;
        vreg[i] = *(const uint4*)&Vbase[(size_t)dd * 2048 + kvc];       // kt=0
    }

    for (int kt = 0; kt <= ktmax; ++kt) {
        __syncthreads();
        #pragma unroll
        for (int i = 0; i < 4; ++i) {
            int c = t + 256 * i;
            int r = c >> 3, col = (c & 7) * 8;
            *(uint4*)&Ks[r * 80 + col] = kreg[i];
            int dd = c >> 4, kvc = (c & 15) * 8;
            *(uint4*)&Vs[dd * 136 + kvc] = vreg[i];
        }
        __syncthreads();

        if (kt < ktmax) {   // prefetch next tile; overlaps compute
            #pragma unroll
            for (int i = 0; i < 4; ++i) {
                int c = t + 256 * i;
                int r = c >> 3, col = (c & 7) * 8;
                kreg[i] = *(const uint4*)&Kbase[(size_t)((kt + 1) * 128 + r) * 64 + col];
                int dd = c >> 4, kvc = (c & 15) * 8;
                vreg[i] = *(const uint4*)&Vbase[(size_t)dd * 2048 + (kt + 1) * 128 + kvc];
            }
        }

        const bool diag = (kt == ktmax);
        #pragma unroll
        for (int s = 0; s < 2; ++s) {
            // S^T = K Q^T  (lane: q = m16, kv = ni*16 + quad*4 + v)
            f32x4 accs[8] = {z, z, z, z, z, z, z, z};
            #pragma unroll
            for (int kk = 0; kk < 2; ++kk)
                #pragma unroll
                for (int ni = 0; ni < 8; ++ni) {
                    bf16x8 bk = *(const bf16x8*)&Ks[(ni * 16 + m16) * 80 + kk * 32 + quad * 8];
                    accs[ni] = MFMA16(bk, fq[s][kk], accs[ni]);
                }

            // p = exp2(s^T): pack to bf16 IN REGISTERS (B-fragment of K=16 mfma)
            const int qg = q0 + s * 64 + w * 16 + m16;
            s16x4 pkv[8];
            #pragma unroll
            for (int ni = 0; ni < 8; ++ni) {
                union { __bf16 b[4]; s16x4 sv; } pk;
                #pragma unroll
                for (int v = 0; v < 4; ++v) {
                    float sc = accs[ni][v];
                    if (diag && (kt * 128 + ni * 16 + quad * 4 + v > qg)) sc = -30000.0f;
                    float pe = __builtin_amdgcn_exp2f(sc);
                    pk.b[v] = (__bf16)pe;
                    lsum[s] += pe;
                }
                pkv[ni] = pk.sv;
            }

            // O^T += V^T P^T : A = V^T b64 fragment, B = pkv (register)
            #pragma unroll
            for (int ni = 0; ni < 8; ++ni) {
                #pragma unroll
                for (int nd = 0; nd < 4; ++nd) {
                    s16x4 va = *(const s16x4*)&Vs[(nd * 16 + m16) * 136 + ni * 16 + quad * 4];
                    acco[s][nd] = MFMA1K(va, pkv[ni], acco[s][nd]);
                }
            }
        }
    }

    // l: reduce per-lane partials across the 4 quads (lanes m16 + 16k)
    #pragma unroll
    for (int s = 0; s < 2; ++s) {
        lsum[s] += __shfl_xor(lsum[s], 16);
        lsum[s] += __shfl_xor(lsum[s], 32);
    }

    // write O back into Ql ([bh][t][64]): lane owns row q = qg, 4 consecutive d
    #pragma unroll
    for (int s = 0; s < 2; ++s) {
        const int qg = q0 + s * 64 + w * 16 + m16;
        const float inv = 1.0f / fmaxf(lsum[s], 1e-30f);
        u16* Orow = &Ql[((size_t)bh * 2048 + qg) * 64];
        #pragma unroll
        for (int nd = 0; nd < 4; ++nd) {
            union { u16 u[4]; uint2 uu; } o;
            #pragma unroll
            for (int v = 0; v < 4; ++v) o.u[v] = f2b(acco[s][nd][v] * inv);
            *(uint2*)&Orow[nd * 16 + quad * 4] = o.uu;
        }
    }
}

// ------- proj GEMM: Y (in Ql layout [bh][t][64]) x WpT[1024,1024]^T + bias -
__global__ __launch_bounds__(256) void k_gemm_proj(
    const u16* __restrict__ Yl, const u16* __restrict__ Bt, const u16* __restrict__ bias,
    const int* __restrict__ flag, void* __restrict__ Out)
{
    constexpr int K = 1024;
    __shared__ __align__(16) u16 As[128 * 64];
    __shared__ __align__(16) u16 Bs[128 * 64];
    const int f32m = *flag;
    const int t = threadIdx.x;
    const int lane = t & 63, w = t >> 6;
    const int quad = lane >> 4, m16 = lane & 15;
    const int wm = (w >> 1) * 64, wn = (w & 1) * 64;
    const int m0 = blockIdx.x * 128, n0 = blockIdx.y * 128;
    const int bb = m0 >> 11, t0 = m0 & 2047;   // block-uniform (128 | 2048)
    const int lr = lane >> 3;
    const int lc = (lane & 7) * 8;

    const f32x4 z = {0.f, 0.f, 0.f, 0.f};
    f32x4 acc[4][4];
    #pragma unroll
    for (int mi = 0; mi < 4; ++mi)
        #pragma unroll
        for (int ni = 0; ni < 4; ++ni) acc[mi][ni] = z;

    for (int k0 = 0; k0 < K; k0 += 64) {
        const int h = k0 >> 6;
        const u16* Abase = Yl + ((size_t)(bb * 16 + h) * 2048 + t0) * 64;
        __syncthreads();
        #pragma unroll
        for (int i = 0; i < 4; ++i) {
            const int chunk = w * 4 + i;               // wave-uniform
            gload_lds16(&Abase[chunk * 512 + lane * 8], &As[chunk * 512]);
            gload_lds16(&Bt[(size_t)(n0 + chunk * 8 + lr) * K + k0 + lc], &Bs[chunk * 512]);
        }
        __syncthreads();
        #pragma unroll
        for (int kk = 0; kk < 2; ++kk) {
            bf16x8 af[4], bfr[4];
            #pragma unroll
            for (int mi = 0; mi < 4; ++mi)
                af[mi] = *(const bf16x8*)&As[(wm + mi * 16 + m16) * 64 + kk * 32 + quad * 8];
            #pragma unroll
            for (int ni = 0; ni < 4; ++ni)
                bfr[ni] = *(const bf16x8*)&Bs[(wn + ni * 16 + m16) * 64 + kk * 32 + quad * 8];
            #pragma unroll
            for (int mi = 0; mi < 4; ++mi)
                #pragma unroll
                for (int ni = 0; ni < 4; ++ni)
                    acc[mi][ni] = MFMA16(af[mi], bfr[ni], acc[mi][ni]);
        }
    }

    #pragma unroll
    for (int mi = 0; mi < 4; ++mi) {
        #pragma unroll
        for (int ni = 0; ni < 4; ++ni) {
            int gn = n0 + wn + ni * 16 + m16;
            float bv = b2f(bias[gn]);
            #pragma unroll
            for (int v = 0; v < 4; ++v) {
                int gm = m0 + wm + mi * 16 + quad * 4 + v;
                float val = acc[mi][ni][v] + bv;
                if (f32m) ((float*)Out)[(size_t)gm * 1024 + gn] = val;
                else      ((u16*)Out)[(size_t)gm * 1024 + gn] = f2b(val);
            }
        }
    }
}

extern "C" void kernel_launch(void* const* d_in, const int* in_sizes, int n_in,
                              void* d_out, int out_size, void* d_ws, size_t ws_size,
                              hipStream_t stream)
{
    (void)in_sizes; (void)n_in; (void)out_size; (void)ws_size;
    const void* x  = d_in[0];   // [8192,1024]  f32 or bf16
    const void* Wa = d_in[1];   // [1024,3072]
    const void* ba = d_in[2];   // [3072]
    const void* Wp = d_in[3];   // [1024,1024]
    const void* bp = d_in[4];   // [1024]
    char* ws = (char*)d_ws;

    // ws: Q/O 16M @0 | K 16M @16M | V 16M @32M | WpT 2M @48M | flag/bpc/bac @50M
    u16* Ql  = (u16*)(ws + 0);
    u16* Kl  = (u16*)(ws + 16777216);
    u16* Vt  = (u16*)(ws + 33554432);
    u16* WpT = (u16*)(ws + 50331648);
    int* flag = (int*)(ws + 52428800);
    u16* bpc  = (u16*)(ws + 52428800 + 256);
    u16* bac  = (u16*)(ws + 52428800 + 256 + 2048);
    // d_out doubles as scratch until proj:
    //   WaT 6M @0 | Abf (bf16 x) 16M @6M (written only in f32 mode, where
    //   out_size = 33.5M; in bf16 mode Abf is never touched and A = x).
    u16* WaT = (u16*)d_out;
    u16* Abf = (u16*)((char*)d_out + 6291456);

    k_detect<<<1, 256, 0, stream>>>((const u16*)x, flag);
    k_cvt_bias<<<1, 256, 0, stream>>>(ba, bp, flag, bac, bpc);
    k_cvt_x<<<4096, 256, 0, stream>>>((const float*)x, flag, Abf);
    k_transpose<<<dim3(48, 16), 256, 0, stream>>>(Wa, WaT, 1024, 3072, flag);
    k_transpose<<<dim3(16, 16), 256, 0, stream>>>(Wp, WpT, 1024, 1024, flag);
    k_gemm_qkv<<<dim3(64, 24), 256, 0, stream>>>(x, Abf, WaT, bac, flag, Ql, Kl, Vt);
    k_attn<<<1024, 256, 0, stream>>>(Ql, Kl, Vt);
    k_gemm_proj<<<dim3(64, 8), 256, 0, stream>>>(Ql, WpT, bpc, flag, d_out);
}